// Round 6
// baseline (319.477 us; speedup 1.0000x reference)
//
#include <hip/hip_runtime.h>
#include <math.h>

#define B_ 4
#define S_ 2048
#define E_ 1024
#define H_ 16
#define D_ 64
#define BH_ (B_ * H_)

// 1/sqrt(64) * log2(e): folded into Wq/bq so QK^T scores are in exp2 domain
#define SCALE_LOG2E 0.18033688011112042f

typedef short short8 __attribute__((ext_vector_type(8)));   // 8 bf16 (4 VGPR)
typedef float f32x4 __attribute__((ext_vector_type(4)));    // MFMA accumulator

static __device__ __forceinline__ unsigned short f2bf(float f) {
    unsigned int u = __float_as_uint(f);
    unsigned int r = (u + 0x7fffu + ((u >> 16) & 1u)) >> 16;
    return (unsigned short)r;
}

// pack two fp32 -> two bf16 (truncation) in one v_perm_b32; low short = lo
static __device__ __forceinline__ unsigned int pack_bf16_trunc(float hi, float lo) {
    return __builtin_amdgcn_perm(__float_as_uint(hi), __float_as_uint(lo), 0x07060302u);
}

// async global->LDS DMA, 16B per lane. LDS dest = base + lane*16 (HW rule).
static __device__ __forceinline__ void gl_lds16(const unsigned short* g, unsigned short* l) {
    __builtin_amdgcn_global_load_lds(
        (const __attribute__((address_space(1))) unsigned int*)g,
        (__attribute__((address_space(3))) unsigned int*)l, 16, 0, 0);
}

// Swizzled LDS layout for [rows][64 shorts] tiles staged by gl_lds16:
// logical 16B-chunk c of row r lives at physical chunk (c ^ (r&7)).
// DMA source chunk for lane L (8 lanes/row): (L&7)^(L>>3).

// ---------------------------------------------------------------------------
// Prep: x fp32 -> bf16, 8 elems/thread
// ---------------------------------------------------------------------------
__global__ __launch_bounds__(256) void xcvt_kernel(
    const float* __restrict__ x, unsigned short* __restrict__ Xb)
{
    size_t i = ((size_t)blockIdx.x * 256 + threadIdx.x) * 8;
    float4 a = *(const float4*)&x[i];
    float4 b = *(const float4*)&x[i + 4];
    ushort4 u0, u1;
    u0.x = f2bf(a.x); u0.y = f2bf(a.y); u0.z = f2bf(a.z); u0.w = f2bf(a.w);
    u1.x = f2bf(b.x); u1.y = f2bf(b.y); u1.z = f2bf(b.z); u1.w = f2bf(b.w);
    *(ushort4*)&Xb[i]     = u0;
    *(ushort4*)&Xb[i + 4] = u1;
}

// ---------------------------------------------------------------------------
// Prep: fused Wq/Wk/Wv transpose fp32 [E][D] -> bf16 [D][E] per head.
// z: 0..15 Wq (scaled), 16..31 Wk, 32..47 Wv.
// ---------------------------------------------------------------------------
__global__ __launch_bounds__(256) void wtrans_qkv_kernel(
    const float* __restrict__ Wq, const float* __restrict__ Wk,
    const float* __restrict__ Wv, unsigned short* __restrict__ Wt)
{
    __shared__ float t[32][33];
    const int tx = threadIdx.x & 31, ty = threadIdx.x >> 5;
    const int r0 = blockIdx.x * 32, c0 = blockIdx.y * 32;
    const int z = blockIdx.z, mtx = z >> 4, h = z & 15;
    const float* s = (mtx == 0 ? Wq : (mtx == 1 ? Wk : Wv)) + (size_t)h * E_ * D_;
    const float scale = (mtx == 0) ? SCALE_LOG2E : 1.0f;
    unsigned short* d = Wt + (size_t)mtx * E_ * E_ + (size_t)h * D_ * E_;
#pragma unroll
    for (int i = 0; i < 4; ++i)
        t[ty + i * 8][tx] = s[(size_t)(r0 + ty + i * 8) * D_ + c0 + tx];
    __syncthreads();
#pragma unroll
    for (int i = 0; i < 4; ++i)
        d[(size_t)(c0 + ty + i * 8) * E_ + r0 + tx] = f2bf(t[tx][ty + i * 8] * scale);
}

// ---------------------------------------------------------------------------
// Prep: transpose fp32 [R][C] -> bf16 [C][R] (Wo)
// ---------------------------------------------------------------------------
__global__ __launch_bounds__(256) void wtrans_kernel(
    const float* __restrict__ src, unsigned short* __restrict__ dst, int R, int C)
{
    __shared__ float t[32][33];
    const int tx = threadIdx.x & 31, ty = threadIdx.x >> 5;
    const int r0 = blockIdx.x * 32, c0 = blockIdx.y * 32;
#pragma unroll
    for (int i = 0; i < 4; ++i)
        t[ty + i * 8][tx] = src[(size_t)(r0 + ty + i * 8) * C + c0 + tx];
    __syncthreads();
#pragma unroll
    for (int i = 0; i < 4; ++i)
        dst[(size_t)(c0 + ty + i * 8) * R + r0 + tx] = f2bf(t[tx][ty + i * 8]);
}

// ---------------------------------------------------------------------------
// Kernel 1: fused QKV projection GEMM, C[8192 x 3072] = Xb * W^T (+bias).
// Double-buffered DMA staging, ONE barrier per K-iter.
// ---------------------------------------------------------------------------
__global__ __launch_bounds__(256) void qkv_gemm_kernel(
    const unsigned short* __restrict__ Xb, const unsigned short* __restrict__ Wt,
    const float* __restrict__ bq, const float* __restrict__ bk,
    const float* __restrict__ bv,
    unsigned short* __restrict__ Qh, unsigned short* __restrict__ Kh,
    unsigned short* __restrict__ Vth)
{
    __shared__ unsigned short As[2][128 * 64];
    __shared__ unsigned short Bs[2][128 * 64];
    const int tid = threadIdx.x;
    const int lane = tid & 63, wid = tid >> 6;
    const int quad = lane >> 4, lc = lane & 15;
    const int wm = wid >> 1, wn = wid & 1;
    const int m0 = blockIdx.y * 128, n0 = blockIdx.x * 128;
    const int l8 = lane >> 3;
    const int sch = ((lane & 7) ^ l8) * 8;     // DMA source chunk (shorts)

    f32x4 acc[4][4];
#pragma unroll
    for (int mt = 0; mt < 4; ++mt)
#pragma unroll
        for (int nt = 0; nt < 4; ++nt)
            acc[mt][nt] = (f32x4){0.f, 0.f, 0.f, 0.f};

    // prologue: stage k0=0 into buffer 0
#pragma unroll
    for (int i = 0; i < 4; ++i) {
        int rw = wid * 32 + i * 8;
        gl_lds16(&Xb[(size_t)(m0 + rw + l8) * E_ + sch], &As[0][rw * 64]);
        gl_lds16(&Wt[(size_t)(n0 + rw + l8) * E_ + sch], &Bs[0][rw * 64]);
    }
    __syncthreads();

    for (int k0 = 0; k0 < E_; k0 += 64) {
        const int cur = (k0 >> 6) & 1;
        if (k0 + 64 < E_) {
#pragma unroll
            for (int i = 0; i < 4; ++i) {
                int rw = wid * 32 + i * 8;
                gl_lds16(&Xb[(size_t)(m0 + rw + l8) * E_ + k0 + 64 + sch], &As[cur ^ 1][rw * 64]);
                gl_lds16(&Wt[(size_t)(n0 + rw + l8) * E_ + k0 + 64 + sch], &Bs[cur ^ 1][rw * 64]);
            }
        }
#pragma unroll
        for (int kc = 0; kc < 2; ++kc) {
            short8 a[4], bfr[4];
#pragma unroll
            for (int mt = 0; mt < 4; ++mt)
                a[mt] = *(const short8*)&As[cur][(wm * 64 + mt * 16 + lc) * 64 +
                                                (((kc * 4 + quad) ^ (lc & 7)) << 3)];
#pragma unroll
            for (int nt = 0; nt < 4; ++nt)
                bfr[nt] = *(const short8*)&Bs[cur][(wn * 64 + nt * 16 + lc) * 64 +
                                                  (((kc * 4 + quad) ^ (lc & 7)) << 3)];
#pragma unroll
            for (int mt = 0; mt < 4; ++mt)
#pragma unroll
                for (int nt = 0; nt < 4; ++nt)
                    acc[mt][nt] = __builtin_amdgcn_mfma_f32_16x16x32_bf16(
                        a[mt], bfr[nt], acc[mt][nt], 0, 0, 0);
        }
        __syncthreads();
    }

    const int nb = n0 + wn * 64;
    const int mtx = nb >> 10;               // 0=Q 1=K 2=V
    const int h = (nb >> 6) & 15;
    const int sg0 = m0 + wm * 64;           // tile rows all in one batch
    const int bb_ = sg0 >> 11;
    if (mtx < 2) {
        const float bsc = (mtx == 0) ? SCALE_LOG2E : 1.0f;
        const float* bias = (mtx == 0 ? bq : bk) + h * D_;
        unsigned short* Out = (mtx == 0) ? Qh : Kh;
#pragma unroll
        for (int nt = 0; nt < 4; ++nt) {
            int d = nt * 16 + lc;
            float bb = bias[d] * bsc;
#pragma unroll
            for (int mt = 0; mt < 4; ++mt)
#pragma unroll
                for (int r = 0; r < 4; ++r) {
                    int ss = (sg0 + mt * 16 + quad * 4 + r) & (S_ - 1);
                    Out[((size_t)(bb_ * H_ + h) * S_ + ss) * D_ + d] =
                        f2bf(acc[mt][nt][r] + bb);
                }
        }
    } else {
        const float* bias = bv + h * D_;
#pragma unroll
        for (int nt = 0; nt < 4; ++nt) {
            int d = nt * 16 + lc;
            float bb = bias[d];
#pragma unroll
            for (int mt = 0; mt < 4; ++mt) {
                int ss0 = (sg0 + mt * 16 + quad * 4) & (S_ - 1);
                ushort4 u;
                u.x = f2bf(acc[mt][nt][0] + bb);
                u.y = f2bf(acc[mt][nt][1] + bb);
                u.z = f2bf(acc[mt][nt][2] + bb);
                u.w = f2bf(acc[mt][nt][3] + bb);
                *(ushort4*)&Vth[(((size_t)bb_ * H_ + h) * D_ + d) * S_ + ss0] = u;
            }
        }
    }
}

// ---------------------------------------------------------------------------
// Kernel 2: flash attention, BARRIER-FREE main loop.
// K/V fragments loaded directly from global (L2-resident: 512KB per bh,
// 8 q-blocks of a bh clustered on one XCD). P round-trip through
// wave-private LDS rows. No __syncthreads after the prologue.
// Block = 4 waves x 64 q-rows; grid (64 bh, 8 qtile) = 512 blocks (2/CU).
// ---------------------------------------------------------------------------
__global__ __launch_bounds__(256, 2) void attn_kernel(
    const unsigned short* __restrict__ Qh, const unsigned short* __restrict__ Kh,
    const unsigned short* __restrict__ Vth, unsigned short* __restrict__ Ch)
{
    __shared__ unsigned short ps[256 * 64];      // P only (wave-private rows)
    const int tid = threadIdx.x;
    const int lane = tid & 63, wid = tid >> 6;
    const int quad = lane >> 4, lc = lane & 15;
    const int bh = blockIdx.x, b = bh >> 4, h = bh & 15;
    const int q0 = blockIdx.y * 256;
    const size_t base  = (size_t)bh * S_ * D_;   // Q/K [bh][s][d]
    const size_t vbase = (size_t)bh * D_ * S_;   // Vt  [bh][d][s]

    // Q fragments: direct global b128 loads (16B contiguous per lane)
    short8 qf[4][2];
#pragma unroll
    for (int mt = 0; mt < 4; ++mt)
#pragma unroll
        for (int kc = 0; kc < 2; ++kc)
            qf[mt][kc] = *(const short8*)&Qh[base +
                (size_t)(q0 + wid * 64 + mt * 16 + lc) * D_ + kc * 32 + quad * 8];

    short8 ones;
#pragma unroll
    for (int i = 0; i < 8; ++i) ones[i] = (short)0x3F80;   // bf16 1.0

    f32x4 ctx[4][4], lacc[4];
#pragma unroll
    for (int mt = 0; mt < 4; ++mt) {
        lacc[mt] = (f32x4){0.f, 0.f, 0.f, 0.f};
#pragma unroll
        for (int nt = 0; nt < 4; ++nt)
            ctx[mt][nt] = (f32x4){0.f, 0.f, 0.f, 0.f};
    }

    for (int kt = 0; kt < S_; kt += 64) {
        // K fragments for this tile: 8 b128 loads from L2
        short8 kf[4][2];
#pragma unroll
        for (int mtK = 0; mtK < 4; ++mtK)
#pragma unroll
            for (int kc = 0; kc < 2; ++kc)
                kf[mtK][kc] = *(const short8*)&Kh[base +
                    (size_t)(kt + mtK * 16 + lc) * D_ + kc * 32 + quad * 8];

        // S^T = K Q^T : [key mtK][q ntQ], scores in exp2 domain
        f32x4 st[4][4];
#pragma unroll
        for (int mtK = 0; mtK < 4; ++mtK)
#pragma unroll
            for (int ntQ = 0; ntQ < 4; ++ntQ)
                st[mtK][ntQ] = (f32x4){0.f, 0.f, 0.f, 0.f};
#pragma unroll
        for (int kc = 0; kc < 2; ++kc)
#pragma unroll
            for (int mtK = 0; mtK < 4; ++mtK)
#pragma unroll
                for (int ntQ = 0; ntQ < 4; ++ntQ)
                    st[mtK][ntQ] = __builtin_amdgcn_mfma_f32_16x16x32_bf16(
                        kf[mtK][kc], qf[ntQ][kc], st[mtK][ntQ], 0, 0, 0);

        // V fragments (issued here so the loads overlap exp/pack/P-write)
        short8 vf[4][2];
#pragma unroll
        for (int nt = 0; nt < 4; ++nt)
#pragma unroll
            for (int kc = 0; kc < 2; ++kc)
                vf[nt][kc] = *(const short8*)&Vth[vbase +
                    (size_t)(nt * 16 + lc) * S_ + kt + kc * 32 + quad * 8];

        // P = exp2(S^T) -> ps[q][key] bf16, swizzled, wave-private rows
#pragma unroll
        for (int ntQ = 0; ntQ < 4; ++ntQ) {
            const int prow = (wid * 64 + ntQ * 16 + lc) * 64 + ((quad & 1) << 2);
#pragma unroll
            for (int mtK = 0; mtK < 4; ++mtK) {
                float p0 = __builtin_amdgcn_exp2f(st[mtK][ntQ][0]);
                float p1 = __builtin_amdgcn_exp2f(st[mtK][ntQ][1]);
                float p2 = __builtin_amdgcn_exp2f(st[mtK][ntQ][2]);
                float p3 = __builtin_amdgcn_exp2f(st[mtK][ntQ][3]);
                uint2 pk;
                pk.x = pack_bf16_trunc(p1, p0);
                pk.y = pack_bf16_trunc(p3, p2);
                *(uint2*)&ps[prow + (((mtK * 2 + (quad >> 1)) ^ (lc & 7)) << 3)] = pk;
            }
        }

        // ctx += P V ; l += P . ones   (pf reads: wave-private, lgkmcnt only)
#pragma unroll
        for (int kc = 0; kc < 2; ++kc) {
            short8 pf[4];
#pragma unroll
            for (int mt = 0; mt < 4; ++mt)
                pf[mt] = *(const short8*)&ps[(wid * 64 + mt * 16 + lc) * 64 +
                                             (((kc * 4 + quad) ^ (lc & 7)) << 3)];
#pragma unroll
            for (int mt = 0; mt < 4; ++mt) {
#pragma unroll
                for (int nt = 0; nt < 4; ++nt)
                    ctx[mt][nt] = __builtin_amdgcn_mfma_f32_16x16x32_bf16(
                        pf[mt], vf[nt][kc], ctx[mt][nt], 0, 0, 0);
                lacc[mt] = __builtin_amdgcn_mfma_f32_16x16x32_bf16(
                    pf[mt], ones, lacc[mt], 0, 0, 0);
            }
        }
    }

    // epilogue: normalize, write CTX in [B,S,E]
#pragma unroll
    for (int mt = 0; mt < 4; ++mt) {
#pragma unroll
        for (int r = 0; r < 4; ++r) {
            float inv = 1.f / lacc[mt][r];
            int row = q0 + wid * 64 + mt * 16 + quad * 4 + r;
#pragma unroll
            for (int nt = 0; nt < 4; ++nt)
                Ch[((size_t)b * S_ + row) * E_ + h * D_ + nt * 16 + lc] =
                    f2bf(ctx[mt][nt][r] * inv);
        }
    }
}

// ---------------------------------------------------------------------------
// Kernel 3: output projection OUT = CTX @ Wo + bo (both bf16, Wo transposed).
// Single-barrier double-buffered structure.
// ---------------------------------------------------------------------------
__global__ __launch_bounds__(256) void out_proj_kernel(
    const unsigned short* __restrict__ Ch, const unsigned short* __restrict__ Wot,
    const float* __restrict__ bo, float* __restrict__ out)
{
    __shared__ unsigned short As[2][128 * 64];
    __shared__ unsigned short Bs[2][128 * 64];
    const int tid = threadIdx.x;
    const int lane = tid & 63, wid = tid >> 6;
    const int quad = lane >> 4, lc = lane & 15;
    const int wm = wid >> 1, wn = wid & 1;
    const int m0 = blockIdx.y * 128, n0 = blockIdx.x * 128;
    const int l8 = lane >> 3;
    const int sch = ((lane & 7) ^ l8) * 8;

    f32x4 acc[4][4];
#pragma unroll
    for (int mt = 0; mt < 4; ++mt)
#pragma unroll
        for (int nt = 0; nt < 4; ++nt)
            acc[mt][nt] = (f32x4){0.f, 0.f, 0.f, 0.f};

#pragma unroll
    for (int i = 0; i < 4; ++i) {
        int rw = wid * 32 + i * 8;
        gl_lds16(&Ch[(size_t)(m0 + rw + l8) * E_ + sch], &As[0][rw * 64]);
        gl_lds16(&Wot[(size_t)(n0 + rw + l8) * E_ + sch], &Bs[0][rw * 64]);
    }
    __syncthreads();

    for (int k0 = 0; k0 < E_; k0 += 64) {
        const int cur = (k0 >> 6) & 1;
        if (k0 + 64 < E_) {
#pragma unroll
            for (int i = 0; i < 4; ++i) {
                int rw = wid * 32 + i * 8;
                gl_lds16(&Ch[(size_t)(m0 + rw + l8) * E_ + k0 + 64 + sch], &As[cur ^ 1][rw * 64]);
                gl_lds16(&Wot[(size_t)(n0 + rw + l8) * E_ + k0 + 64 + sch], &Bs[cur ^ 1][rw * 64]);
            }
        }
#pragma unroll
        for (int kc = 0; kc < 2; ++kc) {
            short8 a[4], bfr[4];
#pragma unroll
            for (int mt = 0; mt < 4; ++mt)
                a[mt] = *(const short8*)&As[cur][(wm * 64 + mt * 16 + lc) * 64 +
                                                (((kc * 4 + quad) ^ (lc & 7)) << 3)];
#pragma unroll
            for (int nt = 0; nt < 4; ++nt)
                bfr[nt] = *(const short8*)&Bs[cur][(wn * 64 + nt * 16 + lc) * 64 +
                                                  (((kc * 4 + quad) ^ (lc & 7)) << 3)];
#pragma unroll
            for (int mt = 0; mt < 4; ++mt)
#pragma unroll
                for (int nt = 0; nt < 4; ++nt)
                    acc[mt][nt] = __builtin_amdgcn_mfma_f32_16x16x32_bf16(
                        a[mt], bfr[nt], acc[mt][nt], 0, 0, 0);
        }
        __syncthreads();
    }

#pragma unroll
    for (int mt = 0; mt < 4; ++mt)
#pragma unroll
        for (int nt = 0; nt < 4; ++nt) {
            int n = n0 + wn * 64 + nt * 16 + lc;
            float bb = bo[n];
#pragma unroll
            for (int r = 0; r < 4; ++r) {
                int row = m0 + wm * 64 + mt * 16 + quad * 4 + r;
                out[(size_t)row * E_ + n] = acc[mt][nt][r] + bb;
            }
        }
}

// ---------------------------------------------------------------------------
extern "C" void kernel_launch(void* const* d_in, const int* in_sizes, int n_in,
                              void* d_out, int out_size, void* d_ws, size_t ws_size,
                              hipStream_t stream)
{
    const float* x  = (const float*)d_in[0];
    const float* Wq = (const float*)d_in[1];
    const float* bq = (const float*)d_in[2];
    const float* Wk = (const float*)d_in[3];
    const float* bk = (const float*)d_in[4];
    const float* Wv = (const float*)d_in[5];
    const float* bv = (const float*)d_in[6];
    const float* Wo = (const float*)d_in[7];
    const float* bo = (const float*)d_in[8];
    (void)in_sizes; (void)n_in; (void)out_size; (void)ws_size;

    const size_t N = (size_t)BH_ * S_ * D_;          // 8,388,608
    unsigned short* Wt  = (unsigned short*)d_ws;     // [3072][1024] bf16
    unsigned short* Wot = Wt + (size_t)3072 * 1024;  // [1024][1024]
    unsigned short* Xb  = Wot + (size_t)1024 * 1024; // [8192][1024]
    unsigned short* Qh  = Xb + N;                    // [bh][s][d]
    unsigned short* Kh  = Qh + N;
    unsigned short* Vth = Kh + N;                    // [bh][d][s]
    unsigned short* Ch  = Vth + N;                   // [B,S,E]

    xcvt_kernel<<<dim3(4096), 256, 0, stream>>>(x, Xb);
    wtrans_qkv_kernel<<<dim3(32, 2, 48), 256, 0, stream>>>(Wq, Wk, Wv, Wt);
    wtrans_kernel<<<dim3(32, 32, 1), 256, 0, stream>>>(Wo, Wot, E_, E_);

    qkv_gemm_kernel<<<dim3(24, 64), 256, 0, stream>>>(Xb, Wt, bq, bk, bv, Qh, Kh, Vth);
    attn_kernel<<<dim3(64, 8), 256, 0, stream>>>(Qh, Kh, Vth, Ch);
    out_proj_kernel<<<dim3(8, 64), 256, 0, stream>>>(Ch, Wot, bo, (float*)d_out);
}

// Round 8
// 275.548 us; speedup vs baseline: 1.1594x; 1.1594x over previous
//
#include <hip/hip_runtime.h>
#include <math.h>

#define B_ 4
#define S_ 2048
#define E_ 1024
#define H_ 16
#define D_ 64
#define BH_ (B_ * H_)

// 1/sqrt(64) * log2(e): folded into Wq/bq so QK^T scores are in exp2 domain
#define SCALE_LOG2E 0.18033688011112042f

typedef short short8 __attribute__((ext_vector_type(8)));   // 8 bf16 (4 VGPR)
typedef float f32x4 __attribute__((ext_vector_type(4)));    // MFMA accumulator

static __device__ __forceinline__ unsigned short f2bf(float f) {
    unsigned int u = __float_as_uint(f);
    unsigned int r = (u + 0x7fffu + ((u >> 16) & 1u)) >> 16;
    return (unsigned short)r;
}

// pack two fp32 -> two bf16 (truncation) in one v_perm_b32; low short = lo
static __device__ __forceinline__ unsigned int pack_bf16_trunc(float hi, float lo) {
    return __builtin_amdgcn_perm(__float_as_uint(hi), __float_as_uint(lo), 0x07060302u);
}

// async global->LDS DMA, 16B per lane. LDS dest = base + lane*16 (HW rule).
static __device__ __forceinline__ void gl_lds16(const unsigned short* g, unsigned short* l) {
    __builtin_amdgcn_global_load_lds(
        (const __attribute__((address_space(1))) unsigned int*)g,
        (__attribute__((address_space(3))) unsigned int*)l, 16, 0, 0);
}

// Swizzled LDS layout for [rows][64 shorts] tiles staged by gl_lds16:
// logical 16B-chunk c of row r lives at physical chunk (c ^ (r&7)).
// DMA source chunk for lane L (8 lanes/row): (L&7)^(L>>3).

// ---------------------------------------------------------------------------
// Prep: x fp32 -> bf16, 8 elems/thread
// ---------------------------------------------------------------------------
__global__ __launch_bounds__(256) void xcvt_kernel(
    const float* __restrict__ x, unsigned short* __restrict__ Xb)
{
    size_t i = ((size_t)blockIdx.x * 256 + threadIdx.x) * 8;
    float4 a = *(const float4*)&x[i];
    float4 b = *(const float4*)&x[i + 4];
    ushort4 u0, u1;
    u0.x = f2bf(a.x); u0.y = f2bf(a.y); u0.z = f2bf(a.z); u0.w = f2bf(a.w);
    u1.x = f2bf(b.x); u1.y = f2bf(b.y); u1.z = f2bf(b.z); u1.w = f2bf(b.w);
    *(ushort4*)&Xb[i]     = u0;
    *(ushort4*)&Xb[i + 4] = u1;
}

// ---------------------------------------------------------------------------
// Prep: fused Wq/Wk/Wv transpose fp32 [E][D] -> bf16 [D][E] per head.
// z: 0..15 Wq (scaled), 16..31 Wk, 32..47 Wv.
// ---------------------------------------------------------------------------
__global__ __launch_bounds__(256) void wtrans_qkv_kernel(
    const float* __restrict__ Wq, const float* __restrict__ Wk,
    const float* __restrict__ Wv, unsigned short* __restrict__ Wt)
{
    __shared__ float t[32][33];
    const int tx = threadIdx.x & 31, ty = threadIdx.x >> 5;
    const int r0 = blockIdx.x * 32, c0 = blockIdx.y * 32;
    const int z = blockIdx.z, mtx = z >> 4, h = z & 15;
    const float* s = (mtx == 0 ? Wq : (mtx == 1 ? Wk : Wv)) + (size_t)h * E_ * D_;
    const float scale = (mtx == 0) ? SCALE_LOG2E : 1.0f;
    unsigned short* d = Wt + (size_t)mtx * E_ * E_ + (size_t)h * D_ * E_;
#pragma unroll
    for (int i = 0; i < 4; ++i)
        t[ty + i * 8][tx] = s[(size_t)(r0 + ty + i * 8) * D_ + c0 + tx];
    __syncthreads();
#pragma unroll
    for (int i = 0; i < 4; ++i)
        d[(size_t)(c0 + ty + i * 8) * E_ + r0 + tx] = f2bf(t[tx][ty + i * 8] * scale);
}

// ---------------------------------------------------------------------------
// Prep: transpose fp32 [R][C] -> bf16 [C][R] (Wo)
// ---------------------------------------------------------------------------
__global__ __launch_bounds__(256) void wtrans_kernel(
    const float* __restrict__ src, unsigned short* __restrict__ dst, int R, int C)
{
    __shared__ float t[32][33];
    const int tx = threadIdx.x & 31, ty = threadIdx.x >> 5;
    const int r0 = blockIdx.x * 32, c0 = blockIdx.y * 32;
#pragma unroll
    for (int i = 0; i < 4; ++i)
        t[ty + i * 8][tx] = src[(size_t)(r0 + ty + i * 8) * C + c0 + tx];
    __syncthreads();
#pragma unroll
    for (int i = 0; i < 4; ++i)
        dst[(size_t)(c0 + ty + i * 8) * R + r0 + tx] = f2bf(t[tx][ty + i * 8]);
}

// ---------------------------------------------------------------------------
// Kernel 1: fused QKV projection GEMM, C[8192 x 3072] = Xb * W^T (+bias).
// Double-buffered DMA staging, ONE barrier per K-iter.
// ---------------------------------------------------------------------------
__global__ __launch_bounds__(256) void qkv_gemm_kernel(
    const unsigned short* __restrict__ Xb, const unsigned short* __restrict__ Wt,
    const float* __restrict__ bq, const float* __restrict__ bk,
    const float* __restrict__ bv,
    unsigned short* __restrict__ Qh, unsigned short* __restrict__ Kh,
    unsigned short* __restrict__ Vth)
{
    __shared__ unsigned short As[2][128 * 64];
    __shared__ unsigned short Bs[2][128 * 64];
    const int tid = threadIdx.x;
    const int lane = tid & 63, wid = tid >> 6;
    const int quad = lane >> 4, lc = lane & 15;
    const int wm = wid >> 1, wn = wid & 1;
    const int m0 = blockIdx.y * 128, n0 = blockIdx.x * 128;
    const int l8 = lane >> 3;
    const int sch = ((lane & 7) ^ l8) * 8;     // DMA source chunk (shorts)

    f32x4 acc[4][4];
#pragma unroll
    for (int mt = 0; mt < 4; ++mt)
#pragma unroll
        for (int nt = 0; nt < 4; ++nt)
            acc[mt][nt] = (f32x4){0.f, 0.f, 0.f, 0.f};

    // prologue: stage k0=0 into buffer 0
#pragma unroll
    for (int i = 0; i < 4; ++i) {
        int rw = wid * 32 + i * 8;
        gl_lds16(&Xb[(size_t)(m0 + rw + l8) * E_ + sch], &As[0][rw * 64]);
        gl_lds16(&Wt[(size_t)(n0 + rw + l8) * E_ + sch], &Bs[0][rw * 64]);
    }
    __syncthreads();

    for (int k0 = 0; k0 < E_; k0 += 64) {
        const int cur = (k0 >> 6) & 1;
        if (k0 + 64 < E_) {
#pragma unroll
            for (int i = 0; i < 4; ++i) {
                int rw = wid * 32 + i * 8;
                gl_lds16(&Xb[(size_t)(m0 + rw + l8) * E_ + k0 + 64 + sch], &As[cur ^ 1][rw * 64]);
                gl_lds16(&Wt[(size_t)(n0 + rw + l8) * E_ + k0 + 64 + sch], &Bs[cur ^ 1][rw * 64]);
            }
        }
#pragma unroll
        for (int kc = 0; kc < 2; ++kc) {
            short8 a[4], bfr[4];
#pragma unroll
            for (int mt = 0; mt < 4; ++mt)
                a[mt] = *(const short8*)&As[cur][(wm * 64 + mt * 16 + lc) * 64 +
                                                (((kc * 4 + quad) ^ (lc & 7)) << 3)];
#pragma unroll
            for (int nt = 0; nt < 4; ++nt)
                bfr[nt] = *(const short8*)&Bs[cur][(wn * 64 + nt * 16 + lc) * 64 +
                                                  (((kc * 4 + quad) ^ (lc & 7)) << 3)];
#pragma unroll
            for (int mt = 0; mt < 4; ++mt)
#pragma unroll
                for (int nt = 0; nt < 4; ++nt)
                    acc[mt][nt] = __builtin_amdgcn_mfma_f32_16x16x32_bf16(
                        a[mt], bfr[nt], acc[mt][nt], 0, 0, 0);
        }
        __syncthreads();
    }

    const int nb = n0 + wn * 64;
    const int mtx = nb >> 10;               // 0=Q 1=K 2=V
    const int h = (nb >> 6) & 15;
    const int sg0 = m0 + wm * 64;           // tile rows all in one batch
    const int bb_ = sg0 >> 11;
    if (mtx < 2) {
        const float bsc = (mtx == 0) ? SCALE_LOG2E : 1.0f;
        const float* bias = (mtx == 0 ? bq : bk) + h * D_;
        unsigned short* Out = (mtx == 0) ? Qh : Kh;
#pragma unroll
        for (int nt = 0; nt < 4; ++nt) {
            int d = nt * 16 + lc;
            float bb = bias[d] * bsc;
#pragma unroll
            for (int mt = 0; mt < 4; ++mt)
#pragma unroll
                for (int r = 0; r < 4; ++r) {
                    int ss = (sg0 + mt * 16 + quad * 4 + r) & (S_ - 1);
                    Out[((size_t)(bb_ * H_ + h) * S_ + ss) * D_ + d] =
                        f2bf(acc[mt][nt][r] + bb);
                }
        }
    } else {
        const float* bias = bv + h * D_;
#pragma unroll
        for (int nt = 0; nt < 4; ++nt) {
            int d = nt * 16 + lc;
            float bb = bias[d];
#pragma unroll
            for (int mt = 0; mt < 4; ++mt) {
                int ss0 = (sg0 + mt * 16 + quad * 4) & (S_ - 1);
                ushort4 u;
                u.x = f2bf(acc[mt][nt][0] + bb);
                u.y = f2bf(acc[mt][nt][1] + bb);
                u.z = f2bf(acc[mt][nt][2] + bb);
                u.w = f2bf(acc[mt][nt][3] + bb);
                *(ushort4*)&Vth[(((size_t)bb_ * H_ + h) * D_ + d) * S_ + ss0] = u;
            }
        }
    }
}

// ---------------------------------------------------------------------------
// Kernel 2: flash attention, no-max streaming softmax. (R5 structure: proven)
// Block = 4 waves x 64 q-rows; grid (64 bh, 8 qtile) -> all q-blocks of a bh
// share an XCD (K/V L2-resident). Double-buffered K/V DMA, ONE barrier/iter:
// prefetch tile kt+64 at iter top, hidden under ~1100cyc of compute.
// [R6 lesson: direct-L2 frag loads regress 46% — LDS staging amortizes L2 BW
//  across 4 waves and keeps DMA latency out of the serial dep chain.]
// ---------------------------------------------------------------------------
__global__ __launch_bounds__(256) void attn_kernel(
    const unsigned short* __restrict__ Qh, const unsigned short* __restrict__ Kh,
    const unsigned short* __restrict__ Vth, unsigned short* __restrict__ Ch)
{
    __shared__ unsigned short ps[256 * 64];     // Q staging, then P (wave-private)
    __shared__ unsigned short ks[2][64 * 64];
    __shared__ unsigned short vt[2][64 * 64];
    const int tid = threadIdx.x;
    const int lane = tid & 63, wid = tid >> 6;
    const int quad = lane >> 4, lc = lane & 15;
    const int bh = blockIdx.x, b = bh >> 4, h = bh & 15;
    const int q0 = blockIdx.y * 256;
    const size_t base  = (size_t)bh * S_ * D_;   // Q/K [bh][s][d]
    const size_t vbase = (size_t)bh * D_ * S_;   // Vt  [bh][d][s]
    const int l8 = lane >> 3;
    const int sch = ((lane & 7) ^ l8) * 8;       // DMA source chunk (shorts)

    // prologue: stage Q tile 256x64 + K/V tile 0 into buffer 0
#pragma unroll
    for (int i = 0; i < 8; ++i) {
        int rw = wid * 64 + i * 8;
        gl_lds16(&Qh[base + (size_t)(q0 + rw + l8) * D_ + sch], &ps[rw * 64]);
    }
#pragma unroll
    for (int i = 0; i < 2; ++i) {
        int rw = wid * 16 + i * 8;
        gl_lds16(&Kh[base + (size_t)(rw + l8) * D_ + sch], &ks[0][rw * 64]);
        gl_lds16(&Vth[vbase + (size_t)(rw + l8) * S_ + sch], &vt[0][rw * 64]);
    }
    __syncthreads();
    short8 qf[4][2];
#pragma unroll
    for (int mt = 0; mt < 4; ++mt)
#pragma unroll
        for (int kc = 0; kc < 2; ++kc)
            qf[mt][kc] = *(const short8*)&ps[(wid * 64 + mt * 16 + lc) * 64 +
                                             (((kc * 4 + quad) ^ (lc & 7)) << 3)];

    short8 ones;
#pragma unroll
    for (int i = 0; i < 8; ++i) ones[i] = (short)0x3F80;   // bf16 1.0

    f32x4 ctx[4][4], lacc[4];
#pragma unroll
    for (int mt = 0; mt < 4; ++mt) {
        lacc[mt] = (f32x4){0.f, 0.f, 0.f, 0.f};
#pragma unroll
        for (int nt = 0; nt < 4; ++nt)
            ctx[mt][nt] = (f32x4){0.f, 0.f, 0.f, 0.f};
    }

    for (int kt = 0; kt < S_; kt += 64) {
        const int cur = (kt >> 6) & 1;
        // prefetch next K/V tile into the other buffer (hidden under compute)
        if (kt + 64 < S_) {
#pragma unroll
            for (int i = 0; i < 2; ++i) {
                int rw = wid * 16 + i * 8;
                gl_lds16(&Kh[base + (size_t)(kt + 64 + rw + l8) * D_ + sch],
                         &ks[cur ^ 1][rw * 64]);
                gl_lds16(&Vth[vbase + (size_t)(rw + l8) * S_ + kt + 64 + sch],
                         &vt[cur ^ 1][rw * 64]);
            }
        }

        // S^T = K Q^T : [key mtK 0..3][q ntQ 0..3], scores in exp2 domain
        f32x4 st[4][4];
#pragma unroll
        for (int mtK = 0; mtK < 4; ++mtK)
#pragma unroll
            for (int ntQ = 0; ntQ < 4; ++ntQ)
                st[mtK][ntQ] = (f32x4){0.f, 0.f, 0.f, 0.f};
#pragma unroll
        for (int kc = 0; kc < 2; ++kc) {
            short8 kf[4];
#pragma unroll
            for (int mtK = 0; mtK < 4; ++mtK)
                kf[mtK] = *(const short8*)&ks[cur][(mtK * 16 + lc) * 64 +
                                                  (((kc * 4 + quad) ^ (lc & 7)) << 3)];
#pragma unroll
            for (int mtK = 0; mtK < 4; ++mtK)
#pragma unroll
                for (int ntQ = 0; ntQ < 4; ++ntQ)
                    st[mtK][ntQ] = __builtin_amdgcn_mfma_f32_16x16x32_bf16(
                        kf[mtK], qf[ntQ][kc], st[mtK][ntQ], 0, 0, 0);
        }

        // P = exp2(S^T) -> ps[q][key] bf16, swizzled, wave-private rows
#pragma unroll
        for (int ntQ = 0; ntQ < 4; ++ntQ) {
            const int prow = (wid * 64 + ntQ * 16 + lc) * 64 + ((quad & 1) << 2);
#pragma unroll
            for (int mtK = 0; mtK < 4; ++mtK) {
                float p0 = __builtin_amdgcn_exp2f(st[mtK][ntQ][0]);
                float p1 = __builtin_amdgcn_exp2f(st[mtK][ntQ][1]);
                float p2 = __builtin_amdgcn_exp2f(st[mtK][ntQ][2]);
                float p3 = __builtin_amdgcn_exp2f(st[mtK][ntQ][3]);
                uint2 pk;
                pk.x = pack_bf16_trunc(p1, p0);
                pk.y = pack_bf16_trunc(p3, p2);
                *(uint2*)&ps[prow + (((mtK * 2 + (quad >> 1)) ^ (lc & 7)) << 3)] = pk;
            }
        }

        // ctx += P V ; l += P . ones
#pragma unroll
        for (int kc = 0; kc < 2; ++kc) {
            short8 pf[4], vf[4];
#pragma unroll
            for (int mt = 0; mt < 4; ++mt)
                pf[mt] = *(const short8*)&ps[(wid * 64 + mt * 16 + lc) * 64 +
                                             (((kc * 4 + quad) ^ (lc & 7)) << 3)];
#pragma unroll
            for (int nt = 0; nt < 4; ++nt)
                vf[nt] = *(const short8*)&vt[cur][(nt * 16 + lc) * 64 +
                                                 (((kc * 4 + quad) ^ (lc & 7)) << 3)];
#pragma unroll
            for (int mt = 0; mt < 4; ++mt) {
#pragma unroll
                for (int nt = 0; nt < 4; ++nt)
                    ctx[mt][nt] = __builtin_amdgcn_mfma_f32_16x16x32_bf16(
                        pf[mt], vf[nt], ctx[mt][nt], 0, 0, 0);
                lacc[mt] = __builtin_amdgcn_mfma_f32_16x16x32_bf16(
                    pf[mt], ones, lacc[mt], 0, 0, 0);
            }
        }
        __syncthreads();   // all waves done with buf[cur]; prefetch DMA drained
    }

    // epilogue: normalize, write CTX in [B,S,E]
#pragma unroll
    for (int mt = 0; mt < 4; ++mt) {
#pragma unroll
        for (int r = 0; r < 4; ++r) {
            float inv = 1.f / lacc[mt][r];
            int row = q0 + wid * 64 + mt * 16 + quad * 4 + r;
#pragma unroll
            for (int nt = 0; nt < 4; ++nt)
                Ch[((size_t)b * S_ + row) * E_ + h * D_ + nt * 16 + lc] =
                    f2bf(ctx[mt][nt][r] * inv);
        }
    }
}

// ---------------------------------------------------------------------------
// Kernel 3: output projection OUT = CTX @ Wo + bo (both bf16, Wo transposed).
// Single-barrier double-buffered structure.
// ---------------------------------------------------------------------------
__global__ __launch_bounds__(256) void out_proj_kernel(
    const unsigned short* __restrict__ Ch, const unsigned short* __restrict__ Wot,
    const float* __restrict__ bo, float* __restrict__ out)
{
    __shared__ unsigned short As[2][128 * 64];
    __shared__ unsigned short Bs[2][128 * 64];
    const int tid = threadIdx.x;
    const int lane = tid & 63, wid = tid >> 6;
    const int quad = lane >> 4, lc = lane & 15;
    const int wm = wid >> 1, wn = wid & 1;
    const int m0 = blockIdx.y * 128, n0 = blockIdx.x * 128;
    const int l8 = lane >> 3;
    const int sch = ((lane & 7) ^ l8) * 8;

    f32x4 acc[4][4];
#pragma unroll
    for (int mt = 0; mt < 4; ++mt)
#pragma unroll
        for (int nt = 0; nt < 4; ++nt)
            acc[mt][nt] = (f32x4){0.f, 0.f, 0.f, 0.f};

#pragma unroll
    for (int i = 0; i < 4; ++i) {
        int rw = wid * 32 + i * 8;
        gl_lds16(&Ch[(size_t)(m0 + rw + l8) * E_ + sch], &As[0][rw * 64]);
        gl_lds16(&Wot[(size_t)(n0 + rw + l8) * E_ + sch], &Bs[0][rw * 64]);
    }
    __syncthreads();

    for (int k0 = 0; k0 < E_; k0 += 64) {
        const int cur = (k0 >> 6) & 1;
        if (k0 + 64 < E_) {
#pragma unroll
            for (int i = 0; i < 4; ++i) {
                int rw = wid * 32 + i * 8;
                gl_lds16(&Ch[(size_t)(m0 + rw + l8) * E_ + k0 + 64 + sch], &As[cur ^ 1][rw * 64]);
                gl_lds16(&Wot[(size_t)(n0 + rw + l8) * E_ + k0 + 64 + sch], &Bs[cur ^ 1][rw * 64]);
            }
        }
#pragma unroll
        for (int kc = 0; kc < 2; ++kc) {
            short8 a[4], bfr[4];
#pragma unroll
            for (int mt = 0; mt < 4; ++mt)
                a[mt] = *(const short8*)&As[cur][(wm * 64 + mt * 16 + lc) * 64 +
                                                (((kc * 4 + quad) ^ (lc & 7)) << 3)];
#pragma unroll
            for (int nt = 0; nt < 4; ++nt)
                bfr[nt] = *(const short8*)&Bs[cur][(wn * 64 + nt * 16 + lc) * 64 +
                                                  (((kc * 4 + quad) ^ (lc & 7)) << 3)];
#pragma unroll
            for (int mt = 0; mt < 4; ++mt)
#pragma unroll
                for (int nt = 0; nt < 4; ++nt)
                    acc[mt][nt] = __builtin_amdgcn_mfma_f32_16x16x32_bf16(
                        a[mt], bfr[nt], acc[mt][nt], 0, 0, 0);
        }
        __syncthreads();
    }

#pragma unroll
    for (int mt = 0; mt < 4; ++mt)
#pragma unroll
        for (int nt = 0; nt < 4; ++nt) {
            int n = n0 + wn * 64 + nt * 16 + lc;
            float bb = bo[n];
#pragma unroll
            for (int r = 0; r < 4; ++r) {
                int row = m0 + wm * 64 + mt * 16 + quad * 4 + r;
                out[(size_t)row * E_ + n] = acc[mt][nt][r] + bb;
            }
        }
}

// ---------------------------------------------------------------------------
extern "C" void kernel_launch(void* const* d_in, const int* in_sizes, int n_in,
                              void* d_out, int out_size, void* d_ws, size_t ws_size,
                              hipStream_t stream)
{
    const float* x  = (const float*)d_in[0];
    const float* Wq = (const float*)d_in[1];
    const float* bq = (const float*)d_in[2];
    const float* Wk = (const float*)d_in[3];
    const float* bk = (const float*)d_in[4];
    const float* Wv = (const float*)d_in[5];
    const float* bv = (const float*)d_in[6];
    const float* Wo = (const float*)d_in[7];
    const float* bo = (const float*)d_in[8];
    (void)in_sizes; (void)n_in; (void)out_size; (void)ws_size;

    const size_t N = (size_t)BH_ * S_ * D_;          // 8,388,608
    unsigned short* Wt  = (unsigned short*)d_ws;     // [3072][1024] bf16
    unsigned short* Wot = Wt + (size_t)3072 * 1024;  // [1024][1024]
    unsigned short* Xb  = Wot + (size_t)1024 * 1024; // [8192][1024]
    unsigned short* Qh  = Xb + N;                    // [bh][s][d]
    unsigned short* Kh  = Qh + N;
    unsigned short* Vth = Kh + N;                    // [bh][d][s]
    unsigned short* Ch  = Vth + N;                   // [B,S,E]

    xcvt_kernel<<<dim3(4096), 256, 0, stream>>>(x, Xb);
    wtrans_qkv_kernel<<<dim3(32, 2, 48), 256, 0, stream>>>(Wq, Wk, Wv, Wt);
    wtrans_kernel<<<dim3(32, 32, 1), 256, 0, stream>>>(Wo, Wot, E_, E_);

    qkv_gemm_kernel<<<dim3(24, 64), 256, 0, stream>>>(Xb, Wt, bq, bk, bv, Qh, Kh, Vth);
    attn_kernel<<<dim3(64, 8), 256, 0, stream>>>(Qh, Kh, Vth, Ch);
    out_proj_kernel<<<dim3(8, 64), 256, 0, stream>>>(Ch, Wot, bo, (float*)d_out);
}